// Round 20
// baseline (2994.612 us; speedup 1.0000x reference)
//
#include <hip/hip_runtime.h>
#include <stdint.h>

// RNNModel: h_{t+1} = hardtanh(x_t @ W_in^T + h_t @ W_h^T), out = h_T @ W_out^T
// B=1024 T=2048 D=13 H=128 O=2, fp32 in/out.
//
// Round 20: ANTI-PHASE two-group pipeline.
//  r19 proved phase-offset co-residency overlaps the serial chain (MfmaUtil
//  58%) but wasted 14/16 columns. Here: ONE block = TWO independent 16-batch
//  groups (8 waves: waves 0-3 group A, 4-7 group B), each r18's structure
//  (swizzled LDS, rotation, self-frag). Step split: S1 = reads + ALL 30 MFMAs;
//  S2 = epilogue + h-write (chain only). Groups offset by one barrier
//  interval: every interval = one group's S1 (582cy MFMA) || other group's S2
//  (~250cy chain, hides). Barriers OUTSIDE the scalarized (readfirstlane)
//  group branch — no divergent-barrier hazard (r11); groups' LDS disjoint.
//  32 blocks x 512 thr; interval ~680-730cy -> step ~1400cy for 32 batches.

#define RNN_B 1024
#define RNN_T 2048
#define RNN_D 13
#define RNN_H 128
#define RNN_O 2

#define NBPG 16               // batches per group
#define NB   32               // 2 groups per block
#define NBLK (RNN_B / NB)     // 32 blocks
#define NTHR 512              // 8 waves

using f32x4 = __attribute__((ext_vector_type(4))) float;
using v8s   = __attribute__((ext_vector_type(8))) short;

__device__ __forceinline__ short f2bf(float f) {           // setup only
    union { float f; uint32_t u; } c; c.f = f;
    uint32_t u = c.u + 0x7fffu + ((c.u >> 16) & 1u);
    return (short)(u >> 16);
}
__device__ __forceinline__ float bf2fs(short s) {
    union { uint32_t u; float f; } c; c.u = ((uint32_t)(uint16_t)s) << 16;
    return c.f;
}
__device__ __forceinline__ float bitf(uint32_t u) {
    union { uint32_t u; float f; } c; c.u = u; return c.f;
}
__device__ __forceinline__ uint32_t cvtpk(float a, float b) {  // [bf16(b)|bf16(a)]
    uint32_t r;
    asm("v_cvt_pk_bf16_f32 %0, %1, %2" : "=v"(r) : "v"(a), "v"(b));
    return r;
}
__device__ __forceinline__ v8s pack4(uint32_t a, uint32_t b, uint32_t c, uint32_t d) {
    union { uint32_t u[4]; v8s s; } z;
    z.u[0] = a; z.u[1] = b; z.u[2] = c; z.u[3] = d; return z.s;
}
__device__ __forceinline__ float clamp1(float v) {
    return __builtin_amdgcn_fmed3f(v, -1.0f, 1.0f);
}

// lgkm-only workgroup barrier (global loads stay in flight across it)
__device__ __forceinline__ void barrier_lgkm() {
    __builtin_amdgcn_sched_barrier(0);
    asm volatile("s_waitcnt lgkmcnt(0)" ::: "memory");
    __builtin_amdgcn_s_barrier();
    asm volatile("" ::: "memory");
    __builtin_amdgcn_sched_barrier(0);
}

#define MFMA(a, b, c) __builtin_amdgcn_mfma_f32_16x16x32_bf16((a), (b), (c), 0, 0, 0)

// S1: all compute for one step. BUFR literal; X0..X3 this parity's x regs;
// TPF = prefetch target step. Writes accs P1..P3 (m-tile0), Q1..Q3 (m-tile1).
#define S1(BUFR, X0, X1, X2, X3, TPF)                                            \
  do {                                                                           \
    v8s bh1 = *(const v8s*)&Hh[BUFR][off1];                                      \
    v8s bl1 = *(const v8s*)&Hl[BUFR][off1];                                      \
    v8s bh2 = *(const v8s*)&Hh[BUFR][off2];                                      \
    v8s bl2 = *(const v8s*)&Hl[BUFR][off2];                                      \
    v8s bh3 = *(const v8s*)&Hh[BUFR][off3];                                      \
    v8s bl3 = *(const v8s*)&Hl[BUFR][off3];                                      \
    float m0 = X0, m1 = X1, m2 = X2, m3 = X3;                                    \
    if (g == 3) { m1 = 0.0f; m2 = 0.0f; m3 = 0.0f; }                             \
    uint32_t xh01 = cvtpk(m0, m1), xh23 = cvtpk(m2, m3);                         \
    float q0 = m0 - bitf(xh01 << 16);                                            \
    float q1 = m1 - bitf(xh01 & 0xffff0000u);                                    \
    float q2 = m2 - bitf(xh23 << 16);                                            \
    float q3 = m3 - bitf(xh23 & 0xffff0000u);                                    \
    uint32_t xl01 = cvtpk(q0, q1), xl23 = cvtpk(q2, q3);                         \
    v8s xh = pack4(xh01, xh23, 0u, 0u);                                          \
    v8s xl = pack4(xl01, xl23, 0u, 0u);                                          \
    f32x4 Z = {0.f, 0.f, 0.f, 0.f};                                              \
    P1 = MFMA(whiA[4], xh, Z);                                                   \
    Q1 = MFMA(whiB[4], xh, Z);                                                   \
    P2 = MFMA(whiA[4], xl, Z);                                                   \
    Q2 = MFMA(whiB[4], xl, Z);                                                   \
    P3 = MFMA(wloA[4], xh, Z);                                                   \
    Q3 = MFMA(wloB[4], xh, Z);                                                   \
    P1 = MFMA(whiA[0], selfBh, P1);                                              \
    Q1 = MFMA(whiB[0], selfBh, Q1);                                              \
    P2 = MFMA(whiA[0], selfBl, P2);                                              \
    Q2 = MFMA(whiB[0], selfBl, Q2);                                              \
    P3 = MFMA(wloA[0], selfBh, P3);                                              \
    Q3 = MFMA(wloB[0], selfBh, Q3);                                              \
    if ((TPF) < RNN_T) {                                                         \
      const float* xp = xrow + (size_t)(TPF) * RNN_D;                            \
      X0 = xp[d0]; X1 = xp[d1]; X2 = xp[d2]; X3 = xp[d3];                        \
    }                                                                            \
    P1 = MFMA(whiA[1], bh1, P1);                                                 \
    Q1 = MFMA(whiB[1], bh1, Q1);                                                 \
    P2 = MFMA(whiA[1], bl1, P2);                                                 \
    Q2 = MFMA(whiB[1], bl1, Q2);                                                 \
    P3 = MFMA(wloA[1], bh1, P3);                                                 \
    Q3 = MFMA(wloB[1], bh1, Q3);                                                 \
    P1 = MFMA(whiA[2], bh2, P1);                                                 \
    Q1 = MFMA(whiB[2], bh2, Q1);                                                 \
    P2 = MFMA(whiA[2], bl2, P2);                                                 \
    Q2 = MFMA(whiB[2], bl2, Q2);                                                 \
    P3 = MFMA(wloA[2], bh2, P3);                                                 \
    Q3 = MFMA(wloB[2], bh2, Q3);                                                 \
    P1 = MFMA(whiA[3], bh3, P1);                                                 \
    Q1 = MFMA(whiB[3], bh3, Q1);                                                 \
    P2 = MFMA(whiA[3], bl3, P2);                                                 \
    Q2 = MFMA(whiB[3], bl3, Q2);                                                 \
    P3 = MFMA(wloA[3], bh3, P3);                                                 \
    Q3 = MFMA(wloB[3], bh3, Q3);                                                 \
  } while (0)

// S2: epilogue + h-write for the step whose MFMAs S1 just did. BUFW literal.
#define S2(BUFW)                                                                 \
  do {                                                                           \
    float v0 = clamp1(P1[0] + P2[0] + P3[0]);                                    \
    float v1 = clamp1(P1[1] + P2[1] + P3[1]);                                    \
    float v2 = clamp1(P1[2] + P2[2] + P3[2]);                                    \
    float v3 = clamp1(P1[3] + P2[3] + P3[3]);                                    \
    uint32_t h01A = cvtpk(v0, v1), h23A = cvtpk(v2, v3);                         \
    float p0 = v0 - bitf(h01A << 16);                                            \
    float p1 = v1 - bitf(h01A & 0xffff0000u);                                    \
    float p2 = v2 - bitf(h23A << 16);                                            \
    float p3 = v3 - bitf(h23A & 0xffff0000u);                                    \
    uint32_t l01A = cvtpk(p0, p1), l23A = cvtpk(p2, p3);                         \
    float w0 = clamp1(Q1[0] + Q2[0] + Q3[0]);                                    \
    float w1 = clamp1(Q1[1] + Q2[1] + Q3[1]);                                    \
    float w2 = clamp1(Q1[2] + Q2[2] + Q3[2]);                                    \
    float w3 = clamp1(Q1[3] + Q2[3] + Q3[3]);                                    \
    uint32_t h01B = cvtpk(w0, w1), h23B = cvtpk(w2, w3);                         \
    float r0 = w0 - bitf(h01B << 16);                                            \
    float r1 = w1 - bitf(h01B & 0xffff0000u);                                    \
    float r2 = w2 - bitf(h23B << 16);                                            \
    float r3 = w3 - bitf(h23B & 0xffff0000u);                                    \
    uint32_t l01B = cvtpk(r0, r1), l23B = cvtpk(r2, r3);                         \
    selfBh = pack4(h01A, h23A, h01B, h23B);                                      \
    selfBl = pack4(l01A, l23A, l01B, l23B);                                      \
    *(v8s*)&Hh[BUFW][offw] = selfBh;                                             \
    *(v8s*)&Hl[BUFW][offw] = selfBl;                                             \
  } while (0)

__global__ __launch_bounds__(NTHR, 1) void rnn_mfma20_kernel(
    const float* __restrict__ xs,     // [B, T, D]
    const float* __restrict__ W_in,   // [H, D]
    const float* __restrict__ W_h,    // [H, H]
    const float* __restrict__ W_out,  // [O, H]
    float* __restrict__ out)          // [B, O]
{
    __shared__ __align__(16) short Hhi[2][2][NBPG * 128];  // [grp][buf][...]
    __shared__ __align__(16) short Hlo[2][2][NBPG * 128];

    const int tid  = threadIdx.x;
    const int lane = tid & 63;
    const int wid  = tid >> 6;                 // 0..7
    const int grp  = __builtin_amdgcn_readfirstlane(wid >> 2);  // scalar 0/1
    const int wg   = wid & 3;                  // role in group; self kt = wg
    const int n    = lane & 15;
    const int g    = lane >> 4;
    const int b0   = blockIdx.x * NB + grp * NBPG;

    short (*Hh)[NBPG * 128] = Hhi[grp];
    short (*Hl)[NBPG * 128] = Hlo[grp];

    // swizzled per-lane short offsets: phys quad = (4*kt + g) ^ n
    const int off1 = n * 128 + (((((wg + 1) & 3) << 2) + g) ^ n) * 8;
    const int off2 = n * 128 + (((((wg + 2) & 3) << 2) + g) ^ n) * 8;
    const int off3 = n * 128 + (((((wg + 3) & 3) << 2) + g) ^ n) * 8;
    const int offw = n * 128 + (((wg << 2) + g) ^ n) * 8;

    // clamped x element indices (d = 4g+j, clamped into [0,12])
    const int d0 = (4 * g + 0 > 12) ? 12 : 4 * g + 0;
    const int d1 = (4 * g + 1 > 12) ? 12 : 4 * g + 1;
    const int d2 = (4 * g + 2 > 12) ? 12 : 4 * g + 2;
    const int d3 = (4 * g + 3 > 12) ? 12 : 4 * g + 3;

    // ---- A fragments, ROTATED: w*[q] <-> kt=(wg+q)&3; index 4 = x tile ----
    v8s whiA[5], wloA[5], whiB[5], wloB[5];
    #pragma unroll
    for (int mi = 0; mi < 2; ++mi) {
        const int row = 16 * (wg * 2 + mi) + n;
        #pragma unroll
        for (int q = 0; q < 4; ++q) {
            const int kt = (wg + q) & 3;
            v8s h8, l8;
            #pragma unroll
            for (int j = 0; j < 4; ++j) {
                const float w1 = W_h[row * RNN_H + 32 * kt + 4 * g + j];
                const float w2 = W_h[row * RNN_H + 32 * kt + 16 + 4 * g + j];
                const short h1 = f2bf(w1);
                const short h2 = f2bf(w2);
                h8[j] = h1; h8[4 + j] = h2;
                l8[j] = f2bf(w1 - bf2fs(h1));
                l8[4 + j] = f2bf(w2 - bf2fs(h2));
            }
            if (mi == 0) { whiA[q] = h8; wloA[q] = l8; }
            else         { whiB[q] = h8; wloB[q] = l8; }
        }
        {   // x tile (index 4)
            v8s h8, l8;
            #pragma unroll
            for (int j = 0; j < 4; ++j) {
                const int kx = 4 * g + j;
                const float w1 = (kx < RNN_D) ? W_in[row * RNN_D + kx] : 0.0f;
                const short h1 = f2bf(w1);
                h8[j] = h1; h8[4 + j] = 0;
                l8[j] = f2bf(w1 - bf2fs(h1));
                l8[4 + j] = 0;
            }
            if (mi == 0) { whiA[4] = h8; wloA[4] = l8; }
            else         { whiB[4] = h8; wloB[4] = l8; }
        }
    }

    // ---- zero-init both groups' buffers ----
    for (int idx = tid; idx < 2 * 2 * NBPG * 128; idx += NTHR) {
        (&Hhi[0][0][0])[idx] = 0;
        (&Hlo[0][0][0])[idx] = 0;
    }

    // ---- persistent state ----
    v8s selfBh = {0, 0, 0, 0, 0, 0, 0, 0};
    v8s selfBl = {0, 0, 0, 0, 0, 0, 0, 0};
    f32x4 P1 = {0.f, 0.f, 0.f, 0.f};
    f32x4 P2 = P1, P3 = P1, Q1 = P1, Q2 = P1, Q3 = P1;

    // ---- x prefetch depth 2, named scalars (per group batches) ----
    const float* xrow = xs + (size_t)(b0 + n) * RNN_T * RNN_D;
    float xa0 = xrow[d0], xa1 = xrow[d1], xa2 = xrow[d2], xa3 = xrow[d3];
    float xb0 = xrow[RNN_D + d0], xb1 = xrow[RNN_D + d1];
    float xb2 = xrow[RNN_D + d2], xb3 = xrow[RNN_D + d3];
    __syncthreads();

    // ---- anti-phase pipeline: 4 barrier intervals per 2 steps ----
    // A: S1(2k,b0) | S2->b1 | S1(2k+1,b1) | S2->b0
    // B: S2->b0*   | S1(2k,b0) | S2->b1   | S1(2k+1,b1)     (*skip at k=0)
    for (int k = 0; k < RNN_T / 2; ++k) {
        const int t2 = 2 * k;
        if (grp == 0) { S1(0, xa0, xa1, xa2, xa3, t2 + 2); }
        else if (k)   { S2(0); }
        barrier_lgkm();
        if (grp == 0) { S2(1); }
        else          { S1(0, xa0, xa1, xa2, xa3, t2 + 2); }
        barrier_lgkm();
        if (grp == 0) { S1(1, xb0, xb1, xb2, xb3, t2 + 3); }
        else          { S2(1); }
        barrier_lgkm();
        if (grp == 0) { S2(0); }
        else          { S1(1, xb0, xb1, xb2, xb3, t2 + 3); }
        barrier_lgkm();
    }
    if (grp == 1) { S2(0); }   // B finishes step T-1 (h_T -> buf0)
    __syncthreads();

    // ---- epilogue: out[b][o] = sum_i W_out[o][i] * h_T[i] (h_T in buf 0) ----
    if (wg == 0 && lane < NBPG * RNN_O) {
        const int nn = lane & 15;
        const int o  = lane >> 4;
        float acc = 0.0f;
        for (int i = 0; i < RNN_H; ++i) {
            const int pos = 32 * (i >> 5) + 8 * ((i >> 2) & 3)
                          + 4 * ((i >> 4) & 1) + (i & 3);
            const int adr = nn * 128 + ((pos >> 3) ^ nn) * 8 + (pos & 7);
            const float hv = bf2fs(Hh[0][adr]) + bf2fs(Hl[0][adr]);
            acc = fmaf(W_out[o * RNN_H + i], hv, acc);
        }
        out[(size_t)(b0 + nn) * RNN_O + o] = acc;
    }
}

extern "C" void kernel_launch(void* const* d_in, const int* in_sizes, int n_in,
                              void* d_out, int out_size, void* d_ws, size_t ws_size,
                              hipStream_t stream) {
    const float* xs    = (const float*)d_in[0];
    const float* W_in  = (const float*)d_in[1];
    const float* W_h   = (const float*)d_in[2];
    const float* W_out = (const float*)d_in[3];
    float* out = (float*)d_out;

    rnn_mfma20_kernel<<<NBLK, NTHR, 0, stream>>>(xs, W_in, W_h, W_out, out);
}

// Round 21
// 1375.627 us; speedup vs baseline: 2.1769x; 2.1769x over previous
//
#include <hip/hip_runtime.h>
#include <stdint.h>

// RNNModel: h_{t+1} = hardtanh(x_t @ W_in^T + h_t @ W_h^T), out = h_T @ W_out^T
// B=1024 T=2048 D=13 H=128 O=2, fp32 in/out.
//
// Round 21 = r18 (best-equal, swizzled LDS, rotation self-fragment) software-
// PIPELINED ACROSS THE BARRIER:
//  Evidence r10/r13/r19/r20: each barrier interval carries ~1000cy of chain;
//  barrier-per-step is provably minimal (h_{t+1} needs all of h_t). The only
//  attackable piece: the write->lgkm-drain->barrier tail is naked stall.
//  New step order: [post-barrier] 6 reads -> x_{t+1} conversion (covers read
//  latency) -> 18 LDS MFMAs -> epilogues -> selfB -> WRITE h -> 12 reg-only
//  MFMAs seeding step t+1 (x-term + self-term; no barrier needed — they use
//  only registers) -> barrier. The 230cy of seeding issue hides the write
//  drain + barrier skew. Accumulators carry across the barrier.
//  Arithmetic value-for-value identical to r18 (absmax must stay 0.0078125).

#define RNN_B 1024
#define RNN_T 2048
#define RNN_D 13
#define RNN_H 128
#define RNN_O 2

#define NB 16
#define NWAVE 4
#define NTHR (NWAVE * 64)

using f32x4 = __attribute__((ext_vector_type(4))) float;
using v8s   = __attribute__((ext_vector_type(8))) short;

__device__ __forceinline__ short f2bf(float f) {           // setup only
    union { float f; uint32_t u; } c; c.f = f;
    uint32_t u = c.u + 0x7fffu + ((c.u >> 16) & 1u);
    return (short)(u >> 16);
}
__device__ __forceinline__ float bf2fs(short s) {
    union { uint32_t u; float f; } c; c.u = ((uint32_t)(uint16_t)s) << 16;
    return c.f;
}
__device__ __forceinline__ float bitf(uint32_t u) {
    union { uint32_t u; float f; } c; c.u = u; return c.f;
}
__device__ __forceinline__ uint32_t cvtpk(float a, float b) {  // [bf16(b)|bf16(a)]
    uint32_t r;
    asm("v_cvt_pk_bf16_f32 %0, %1, %2" : "=v"(r) : "v"(a), "v"(b));
    return r;
}
__device__ __forceinline__ v8s pack4(uint32_t a, uint32_t b, uint32_t c, uint32_t d) {
    union { uint32_t u[4]; v8s s; } z;
    z.u[0] = a; z.u[1] = b; z.u[2] = c; z.u[3] = d; return z.s;
}
__device__ __forceinline__ float clamp1(float v) {
    return __builtin_amdgcn_fmed3f(v, -1.0f, 1.0f);
}

// lgkm-only workgroup barrier, fenced (r15: fences are load-bearing)
__device__ __forceinline__ void barrier_lgkm() {
    __builtin_amdgcn_sched_barrier(0);
    asm volatile("s_waitcnt lgkmcnt(0)" ::: "memory");
    __builtin_amdgcn_s_barrier();
    asm volatile("" ::: "memory");
    __builtin_amdgcn_sched_barrier(0);
}

#define MFMA(a, b, c) __builtin_amdgcn_mfma_f32_16x16x32_bf16((a), (b), (c), 0, 0, 0)

// convert raw x scalars (C0..C3) into bf16 hi/lo B-fragments XH/XL
#define XCONV(XH, XL, C0, C1, C2, C3)                                            \
  do {                                                                           \
    float cm0 = C0, cm1 = C1, cm2 = C2, cm3 = C3;                                \
    if (g == 3) { cm1 = 0.0f; cm2 = 0.0f; cm3 = 0.0f; }                          \
    uint32_t ch01 = cvtpk(cm0, cm1), ch23 = cvtpk(cm2, cm3);                     \
    float cq0 = cm0 - bitf(ch01 << 16);                                          \
    float cq1 = cm1 - bitf(ch01 & 0xffff0000u);                                  \
    float cq2 = cm2 - bitf(ch23 << 16);                                          \
    float cq3 = cm3 - bitf(ch23 & 0xffff0000u);                                  \
    uint32_t cl01 = cvtpk(cq0, cq1), cl23 = cvtpk(cq2, cq3);                     \
    XH = pack4(ch01, ch23, 0u, 0u);                                              \
    XL = pack4(cl01, cl23, 0u, 0u);                                              \
  } while (0)

// 12 register-only MFMAs seeding step accs from x-frag (XH,XL) + selfB
#define SEED(XH, XL)                                                             \
  do {                                                                           \
    f32x4 Z = {0.f, 0.f, 0.f, 0.f};                                              \
    A1 = MFMA(whiA[4], XH, Z);                                                   \
    B1 = MFMA(whiB[4], XH, Z);                                                   \
    A2 = MFMA(whiA[4], XL, Z);                                                   \
    B2 = MFMA(whiB[4], XL, Z);                                                   \
    A3 = MFMA(wloA[4], XH, Z);                                                   \
    B3 = MFMA(wloB[4], XH, Z);                                                   \
    A1 = MFMA(whiA[0], selfBh, A1);                                              \
    B1 = MFMA(whiB[0], selfBh, B1);                                              \
    A2 = MFMA(whiA[0], selfBl, A2);                                              \
    B2 = MFMA(whiB[0], selfBl, B2);                                              \
    A3 = MFMA(wloA[0], selfBh, A3);                                              \
    B3 = MFMA(wloB[0], selfBh, B3);                                              \
  } while (0)

// One pipelined step. On entry (post-barrier): h_t visible in buf CUR; accs
// A*,B* already seeded with x_t + self terms. C0..C3 = raw x_{t+1} (converted
// here); P0..P3 = raw slot refilled with x[TPF] (depth-2).
#define STEPP(CUR, NXT, C0, C1, C2, C3, P0, P1, P2, P3, TPF)                     \
  do {                                                                           \
    /* 1) reads of the 3 other kt slices of h_t */                               \
    v8s bh1 = *(const v8s*)&Hhi[CUR][off1];                                      \
    v8s bl1 = *(const v8s*)&Hlo[CUR][off1];                                      \
    v8s bh2 = *(const v8s*)&Hhi[CUR][off2];                                      \
    v8s bl2 = *(const v8s*)&Hlo[CUR][off2];                                      \
    v8s bh3 = *(const v8s*)&Hhi[CUR][off3];                                      \
    v8s bl3 = *(const v8s*)&Hlo[CUR][off3];                                      \
    /* 2) convert x_{t+1} (VALU; covers read latency) */                         \
    v8s xhn, xln;                                                                \
    XCONV(xhn, xln, C0, C1, C2, C3);                                             \
    /* 3) 18 LDS-dependent MFMAs into carried accs */                            \
    A1 = MFMA(whiA[1], bh1, A1);                                                 \
    B1 = MFMA(whiB[1], bh1, B1);                                                 \
    A2 = MFMA(whiA[1], bl1, A2);                                                 \
    B2 = MFMA(whiB[1], bl1, B2);                                                 \
    A3 = MFMA(wloA[1], bh1, A3);                                                 \
    B3 = MFMA(wloB[1], bh1, B3);                                                 \
    A1 = MFMA(whiA[2], bh2, A1);                                                 \
    B1 = MFMA(whiB[2], bh2, B1);                                                 \
    A2 = MFMA(whiA[2], bl2, A2);                                                 \
    B2 = MFMA(whiB[2], bl2, B2);                                                 \
    A3 = MFMA(wloA[2], bh2, A3);                                                 \
    B3 = MFMA(wloB[2], bh2, B3);                                                 \
    A1 = MFMA(whiA[3], bh3, A1);                                                 \
    B1 = MFMA(whiB[3], bh3, B1);                                                 \
    A2 = MFMA(whiA[3], bl3, A2);                                                 \
    B2 = MFMA(whiB[3], bl3, B2);                                                 \
    A3 = MFMA(wloA[3], bh3, A3);                                                 \
    B3 = MFMA(wloB[3], bh3, B3);                                                 \
    /* 4) A epilogue */                                                          \
    float v0 = clamp1(A1[0] + A2[0] + A3[0]);                                    \
    float v1 = clamp1(A1[1] + A2[1] + A3[1]);                                    \
    float v2 = clamp1(A1[2] + A2[2] + A3[2]);                                    \
    float v3 = clamp1(A1[3] + A2[3] + A3[3]);                                    \
    uint32_t h01A = cvtpk(v0, v1), h23A = cvtpk(v2, v3);                         \
    float p0 = v0 - bitf(h01A << 16);                                            \
    float p1 = v1 - bitf(h01A & 0xffff0000u);                                    \
    float p2 = v2 - bitf(h23A << 16);                                            \
    float p3 = v3 - bitf(h23A & 0xffff0000u);                                    \
    uint32_t l01A = cvtpk(p0, p1), l23A = cvtpk(p2, p3);                         \
    /* 5) B epilogue; selfB = combined fragment */                               \
    float w0 = clamp1(B1[0] + B2[0] + B3[0]);                                    \
    float w1 = clamp1(B1[1] + B2[1] + B3[1]);                                    \
    float w2 = clamp1(B1[2] + B2[2] + B3[2]);                                    \
    float w3 = clamp1(B1[3] + B2[3] + B3[3]);                                    \
    uint32_t h01B = cvtpk(w0, w1), h23B = cvtpk(w2, w3);                         \
    float r0 = w0 - bitf(h01B << 16);                                            \
    float r1 = w1 - bitf(h01B & 0xffff0000u);                                    \
    float r2 = w2 - bitf(h23B << 16);                                            \
    float r3 = w3 - bitf(h23B & 0xffff0000u);                                    \
    uint32_t l01B = cvtpk(r0, r1), l23B = cvtpk(r2, r3);                         \
    selfBh = pack4(h01A, h23A, h01B, h23B);                                      \
    selfBl = pack4(l01A, l23A, l01B, l23B);                                      \
    /* 6) write h_{t+1} EARLY (drain overlaps the seeding below) */              \
    *(v8s*)&Hhi[NXT][offw] = selfBh;                                             \
    *(v8s*)&Hlo[NXT][offw] = selfBl;                                             \
    /* 7) 12 reg-only MFMAs seed step t+1 (pre-barrier; hides drain+skew) */     \
    SEED(xhn, xln);                                                              \
    /* 8) raw x prefetch depth 2 (vmcnt, never drained in-loop) */               \
    if ((TPF) < RNN_T) {                                                         \
      const float* xp = xrow + (size_t)(TPF) * RNN_D;                            \
      P0 = xp[d0]; P1 = xp[d1]; P2 = xp[d2]; P3 = xp[d3];                        \
    }                                                                            \
    /* 9) rendezvous */                                                          \
    barrier_lgkm();                                                              \
  } while (0)

__global__ __launch_bounds__(NTHR, 1) void rnn_mfma21_kernel(
    const float* __restrict__ xs,     // [B, T, D]
    const float* __restrict__ W_in,   // [H, D]
    const float* __restrict__ W_h,    // [H, H]
    const float* __restrict__ W_out,  // [O, H]
    float* __restrict__ out)          // [B, O]
{
    __shared__ __align__(16) short Hhi[2][NB * 128];
    __shared__ __align__(16) short Hlo[2][NB * 128];

    const int tid  = threadIdx.x;
    const int lane = tid & 63;
    const int wid  = tid >> 6;       // wave 0..3; self kt = wid
    const int n    = lane & 15;      // batch col / A-row within tile
    const int g    = lane >> 4;      // k-group 0..3
    const int b0   = blockIdx.x * NB;

    // swizzled per-lane short offsets: phys quad = (4*kt + g) ^ n
    const int off1 = n * 128 + (((((wid + 1) & 3) << 2) + g) ^ n) * 8;
    const int off2 = n * 128 + (((((wid + 2) & 3) << 2) + g) ^ n) * 8;
    const int off3 = n * 128 + (((((wid + 3) & 3) << 2) + g) ^ n) * 8;
    const int offw = n * 128 + (((wid << 2) + g) ^ n) * 8;

    // clamped x element indices for this lane (d = 4g+j, clamped into [0,12])
    const int d0 = (4 * g + 0 > 12) ? 12 : 4 * g + 0;
    const int d1 = (4 * g + 1 > 12) ? 12 : 4 * g + 1;
    const int d2 = (4 * g + 2 > 12) ? 12 : 4 * g + 2;
    const int d3 = (4 * g + 3 > 12) ? 12 : 4 * g + 3;

    // ---- A fragments, ROTATED: wA[q] <-> kt=(wid+q)&3; index 4 = x tile ----
    v8s whiA[5], wloA[5], whiB[5], wloB[5];
    #pragma unroll
    for (int mi = 0; mi < 2; ++mi) {
        const int row = 16 * (wid * 2 + mi) + n;
        #pragma unroll
        for (int q = 0; q < 4; ++q) {
            const int kt = (wid + q) & 3;          // runtime; addresses only
            v8s h8, l8;
            #pragma unroll
            for (int j = 0; j < 4; ++j) {
                const float w1 = W_h[row * RNN_H + 32 * kt + 4 * g + j];
                const float w2 = W_h[row * RNN_H + 32 * kt + 16 + 4 * g + j];
                const short h1 = f2bf(w1);
                const short h2 = f2bf(w2);
                h8[j] = h1; h8[4 + j] = h2;
                l8[j] = f2bf(w1 - bf2fs(h1));
                l8[4 + j] = f2bf(w2 - bf2fs(h2));
            }
            if (mi == 0) { whiA[q] = h8; wloA[q] = l8; }
            else         { whiB[q] = h8; wloB[q] = l8; }
        }
        {   // x tile (index 4)
            v8s h8, l8;
            #pragma unroll
            for (int j = 0; j < 4; ++j) {
                const int kx = 4 * g + j;
                const float w1 = (kx < RNN_D) ? W_in[row * RNN_D + kx] : 0.0f;
                const short h1 = f2bf(w1);
                h8[j] = h1; h8[4 + j] = 0;
                l8[j] = f2bf(w1 - bf2fs(h1));
                l8[4 + j] = 0;
            }
            if (mi == 0) { whiA[4] = h8; wloA[4] = l8; }
            else         { whiB[4] = h8; wloB[4] = l8; }
        }
    }

    // ---- zero-init buffer 0 (h0 = 0) ----
    for (int idx = tid; idx < NB * 128; idx += NTHR) {
        Hhi[0][idx] = 0;
        Hlo[0][idx] = 0;
    }

    // ---- self B-fragment (kt = wid) starts at h0 = 0 ----
    v8s selfBh = {0, 0, 0, 0, 0, 0, 0, 0};
    v8s selfBl = {0, 0, 0, 0, 0, 0, 0, 0};

    // ---- raw x prefetch depth 2 ----
    const float* xrow = xs + (size_t)(b0 + n) * RNN_T * RNN_D;
    float xa0 = xrow[d0], xa1 = xrow[d1], xa2 = xrow[d2], xa3 = xrow[d3];
    float xb0 = xrow[RNN_D + d0], xb1 = xrow[RNN_D + d1];
    float xb2 = xrow[RNN_D + d2], xb3 = xrow[RNN_D + d3];

    // ---- pipeline prologue: convert x_0, seed step-0 accs ----
    f32x4 A1, A2, A3, B1, B2, B3;
    {
        v8s xh0, xl0;
        XCONV(xh0, xl0, xa0, xa1, xa2, xa3);
        SEED(xh0, xl0);
    }
    __syncthreads();   // h0 (zeros) visible; step 0 may read

    // ---- recurrence: x2 unrolled; even step converts xb, refills xa ----
    for (int t = 0; t < RNN_T; t += 2) {
        STEPP(0, 1, xb0, xb1, xb2, xb3, xa0, xa1, xa2, xa3, t + 2);
        STEPP(1, 0, xa0, xa1, xa2, xa3, xb0, xb1, xb2, xb3, t + 3);
    }
    // (trailing SEED of step T is dead work; its accs are discarded)

    __syncthreads();  // full sync once before epilogue

    // ---- epilogue: out[b][o] = sum_i W_out[o][i] * h_T[i]  (h_T in buf 0) ----
    if (wid == 0 && lane < NB * RNN_O) {
        const int nn = lane & 15;
        const int o  = lane >> 4;
        float acc = 0.0f;
        for (int i = 0; i < RNN_H; ++i) {
            const int pos = 32 * (i >> 5) + 8 * ((i >> 2) & 3)
                          + 4 * ((i >> 4) & 1) + (i & 3);
            const int adr = nn * 128 + ((pos >> 3) ^ nn) * 8 + (pos & 7);
            const float hv = bf2fs(Hhi[0][adr]) + bf2fs(Hlo[0][adr]);
            acc = fmaf(W_out[o * RNN_H + i], hv, acc);
        }
        out[(size_t)(b0 + nn) * RNN_O + o] = acc;
    }
}

extern "C" void kernel_launch(void* const* d_in, const int* in_sizes, int n_in,
                              void* d_out, int out_size, void* d_ws, size_t ws_size,
                              hipStream_t stream) {
    const float* xs    = (const float*)d_in[0];
    const float* W_in  = (const float*)d_in[1];
    const float* W_h   = (const float*)d_in[2];
    const float* W_out = (const float*)d_in[3];
    float* out = (float*)d_out;

    rnn_mfma21_kernel<<<RNN_B / NB, NTHR, 0, stream>>>(xs, W_in, W_h, W_out, out);
}